// Round 8
// baseline (151.769 us; speedup 1.0000x reference)
//
#include <hip/hip_runtime.h>
#include <hip/hip_bf16.h>
#include <math.h>

#define BATCH   8192
#define NFIELD  24
#define FAC     16
#define PAIRS   276
#define NSETS   48             // 46 real 6-pair sets + 2 idle sets
#define SETLEN  6
#define NBB     (BATCH / 64)   // 128 batch blocks of 64 rows
#define SGROUPS 6              // 8 waves per block => 48 sets

typedef __attribute__((ext_vector_type(8))) __bf16 bf16x8;
typedef __attribute__((ext_vector_type(4))) float f32x4;

// ---- workspace layout (bytes) ----
// xvT:   [128][24][2][64][8] bf16 = 6,291,456
// combo: [276 + 2 pad][4608]      = 1,281,024 (+pad)
// partial:[48][8192] f32          = 1,572,864
// consts: [1] f32
#define XVT_OFF   0
#define COMBO_OFF 6291456
#define PART_OFF  (COMBO_OFF + 1285632)
#define CONST_OFF (PART_OFF + 1572864)

// Fused prep: blocks [0,768) gather v->xvT; blocks [768,837) repack weights.
__global__ void prep_all(const int* __restrict__ inputs,
                         const float* __restrict__ v,
                         const float* __restrict__ W1,
                         const float* __restrict__ W2,
                         const float* __restrict__ b1,
                         const float* __restrict__ b2,
                         const float* __restrict__ bsc,
                         __hip_bfloat16* __restrict__ xvT,
                         char* __restrict__ combo,
                         float* __restrict__ consts) {
    __shared__ float red[256];
    int blk = blockIdx.x;
    if (blk < 768) {
        int t = blk * 256 + threadIdx.x;          // < 196608
        int field = t >> 13;
        int b = t & 8191;
        int idx = inputs[b * NFIELD + field];
        const float4* src = (const float4*)(v + (long)idx * FAC);
        union { __hip_bfloat16 h[16]; uint4 u[2]; } tmp;
        float4 a0 = src[0], a1 = src[1], a2 = src[2], a3 = src[3];
        tmp.h[0]  = __float2bfloat16(a0.x); tmp.h[1]  = __float2bfloat16(a0.y);
        tmp.h[2]  = __float2bfloat16(a0.z); tmp.h[3]  = __float2bfloat16(a0.w);
        tmp.h[4]  = __float2bfloat16(a1.x); tmp.h[5]  = __float2bfloat16(a1.y);
        tmp.h[6]  = __float2bfloat16(a1.z); tmp.h[7]  = __float2bfloat16(a1.w);
        tmp.h[8]  = __float2bfloat16(a2.x); tmp.h[9]  = __float2bfloat16(a2.y);
        tmp.h[10] = __float2bfloat16(a2.z); tmp.h[11] = __float2bfloat16(a2.w);
        tmp.h[12] = __float2bfloat16(a3.x); tmp.h[13] = __float2bfloat16(a3.y);
        tmp.h[14] = __float2bfloat16(a3.z); tmp.h[15] = __float2bfloat16(a3.w);
        int bb = b >> 6, row = b & 63;
        __hip_bfloat16* base = xvT + (long)bb * 24576 + field * 1024 + row * 8;
        *(uint4*)base         = tmp.u[0];
        *(uint4*)(base + 512) = tmp.u[1];
    } else {
        int wb = blk - 768;                        // 0..68
        int t = wb * 256 + threadIdx.x;            // < 17664
        int p = t >> 6;
        int L = t & 63;
        int q = L >> 4, c = L & 15;
        char* base = combo + (long)p * 4608;
        union { __hip_bfloat16 h[8]; uint4 u; } buf;
#pragma unroll
        for (int tt = 0; tt < 4; ++tt) {
#pragma unroll
            for (int jj = 0; jj < 8; ++jj)
                buf.h[jj] = __float2bfloat16(W1[p * 2048 + (q * 8 + jj) * 64 + tt * 16 + c]);
            *(uint4*)(base + 512 + tt * 1024 + L * 16) = buf.u;
        }
        if (L < 16) {
            float4 bv = {b1[p * 64 + L], b1[p * 64 + 16 + L], b1[p * 64 + 32 + L], b1[p * 64 + 48 + L]};
            *(float4*)(base + L * 16) = bv;
            float4 wv = {W2[p * 64 + L], W2[p * 64 + 16 + L], W2[p * 64 + 32 + L], W2[p * 64 + 48 + L]};
            *(float4*)(base + 256 + L * 16) = wv;
        }
        if (wb == 1) {   // zero the 2 pad pairs
            uint4 z = {0, 0, 0, 0};
            for (int k = threadIdx.x; k < 576; k += 256)
                *(uint4*)(combo + (long)PAIRS * 4608 + k * 16) = z;
        }
        if (wb == 0) {
            float s = 0.f;
            for (int k = threadIdx.x; k < PAIRS; k += 256) s += b2[k];
            red[threadIdx.x] = s;
            __syncthreads();
            for (int off = 128; off > 0; off >>= 1) {
                if (threadIdx.x < off) red[threadIdx.x] += red[threadIdx.x + off];
                __syncthreads();
            }
            if (threadIdx.x == 0) consts[0] = red[0] + bsc[0];
        }
    }
}

// 512-thread blocks (8 waves) share one 64-row slab: 48KB LDS -> 3 blocks/CU
// = 24 waves/CU = 6 waves/SIMD (2x the TLP of the 256-thread variant).
// Each wave owns a distinct 6-pair set; no software prefetch (rolled loop,
// pure TLP latency hiding); VGPR kept <= 85 via __launch_bounds__(512,6).
__global__ __launch_bounds__(512, 6) void ffm_main(
        const __hip_bfloat16* __restrict__ xvT,
        const char* __restrict__ combo,
        float* __restrict__ partial) {
    // [field][half][row64][8] with +32 elem (64B) pad per 512-elem half-group
    __shared__ __align__(16) __hip_bfloat16 xv_s[24 * 1088];  // 51 KB

    int tid  = threadIdx.x;
    int bb   = blockIdx.x & (NBB - 1);
    int sg   = blockIdx.x >> 7;          // 0..5
    int lane = tid & 63;
    int wave = tid >> 6;                 // 0..7
    int col  = lane & 15;
    int quad = lane >> 4;

    // stage 48KB slab: 3072 16B chunks, swizzle ch -> elem ch*8 + (ch>>6)*32
    {
        const uint4* src = (const uint4*)(xvT + (long)bb * 24576);
#pragma unroll
        for (int it = 0; it < 6; ++it) {
            int ch = tid + it * 512;
            *(uint4*)(xv_s + ch * 8 + (ch >> 6) * 32) = src[ch];
        }
    }
    __syncthreads();

    int setid = sg * 8 + wave;           // 0..47; sets 46,47 idle
    f32x4 acc[4];
#pragma unroll
    for (int t = 0; t < 4; ++t) acc[t] = (f32x4){0.f, 0.f, 0.f, 0.f};

    const int abase = (quad & 1) * 544 + col * 8;   // + t*128 per row-tile
    const int mcol  = col * 16;
    const int l16   = lane * 16;
    const f32x4 z4  = {0.f, 0.f, 0.f, 0.f};

    if (setid < 46) {
        int p0 = setid * SETLEN;
        int i = 0, rem = p0;
        while (rem >= NFIELD - 1 - i) { rem -= NFIELD - 1 - i; ++i; }
        int j = i + 1 + rem;

        const char* wp = combo + (long)p0 * 4608;
#pragma unroll 1
        for (int k = 0; k < SETLEN; ++k) {
            // load this pair's package (no prefetch: TLP hides the latency)
            float4 tb = *(const float4*)(wp + mcol);
            f32x4 cb0 = {tb.x, tb.x, tb.x, tb.x};
            f32x4 cb1 = {tb.y, tb.y, tb.y, tb.y};
            f32x4 cb2 = {tb.z, tb.z, tb.z, tb.z};
            f32x4 cb3 = {tb.w, tb.w, tb.w, tb.w};
            float4 mw = *(const float4*)(wp + 256 + mcol);
            bf16x8 f0 = *(const bf16x8*)(wp + 512  + l16);
            bf16x8 f1 = *(const bf16x8*)(wp + 1536 + l16);
            bf16x8 f2 = *(const bf16x8*)(wp + 2560 + l16);
            bf16x8 f3 = *(const bf16x8*)(wp + 3584 + l16);

            int fso = ((quad < 2) ? i : j) * 1088;
#pragma unroll
            for (int t = 0; t < 4; ++t) {
                bf16x8 af = *(const bf16x8*)(xv_s + fso + abase + t * 128);
                f32x4 c0 = __builtin_amdgcn_mfma_f32_16x16x32_bf16(af, f0, cb0, 0, 0, 0);
                f32x4 c1 = __builtin_amdgcn_mfma_f32_16x16x32_bf16(af, f1, cb1, 0, 0, 0);
                f32x4 c2 = __builtin_amdgcn_mfma_f32_16x16x32_bf16(af, f2, cb2, 0, 0, 0);
                f32x4 c3 = __builtin_amdgcn_mfma_f32_16x16x32_bf16(af, f3, cb3, 0, 0, 0);
                acc[t] = acc[t] + __builtin_elementwise_max(c0, z4) * mw.x;
                acc[t] = acc[t] + __builtin_elementwise_max(c1, z4) * mw.y;
                acc[t] = acc[t] + __builtin_elementwise_max(c2, z4) * mw.z;
                acc[t] = acc[t] + __builtin_elementwise_max(c3, z4) * mw.w;
            }
            wp += 4608;
            ++j;
            if (j == NFIELD) { ++i; j = i + 1; }
        }
    }

    // reduce each acc component over the 16 column-lanes within its quad group
#pragma unroll
    for (int m = 1; m < 16; m <<= 1) {
#pragma unroll
        for (int t = 0; t < 4; ++t) {
#pragma unroll
            for (int r = 0; r < 4; ++r) acc[t][r] += __shfl_xor(acc[t][r], m, 64);
        }
    }
    if (col == 0) {
#pragma unroll
        for (int t = 0; t < 4; ++t) {
            f32x4 o = acc[t];
            *(f32x4*)&partial[setid * BATCH + bb * 64 + t * 16 + quad * 4] = o;
        }
    }
}

__global__ void finalize(const int* __restrict__ inputs,
                         const float* __restrict__ w,
                         const float* __restrict__ consts,
                         const float* __restrict__ partial,
                         float* __restrict__ out) {
    int bidx = blockIdx.x * 256 + threadIdx.x;   // < 8192
    const int4* ip = (const int4*)(inputs + bidx * NFIELD);
    float l = 0.f;
#pragma unroll
    for (int q = 0; q < 6; ++q) {
        int4 v4 = ip[q];
        l += w[v4.x] + w[v4.y] + w[v4.z] + w[v4.w];
    }
    float s = l + consts[0];
#pragma unroll 4
    for (int g = 0; g < NSETS; ++g) s += partial[g * BATCH + bidx];
    out[bidx] = 1.0f / (1.0f + expf(-s));
}

extern "C" void kernel_launch(void* const* d_in, const int* in_sizes, int n_in,
                              void* d_out, int out_size, void* d_ws, size_t ws_size,
                              hipStream_t stream) {
    const int*   inputs = (const int*)d_in[0];
    const float* w      = (const float*)d_in[1];
    const float* v      = (const float*)d_in[2];
    const float* bsc    = (const float*)d_in[3];
    const float* W1     = (const float*)d_in[4];
    const float* b1     = (const float*)d_in[5];
    const float* W2     = (const float*)d_in[6];
    const float* b2     = (const float*)d_in[7];
    float* out = (float*)d_out;

    char* ws = (char*)d_ws;
    __hip_bfloat16* xvT = (__hip_bfloat16*)(ws + XVT_OFF);
    char*  combo   = ws + COMBO_OFF;
    float* partial = (float*)(ws + PART_OFF);
    float* consts  = (float*)(ws + CONST_OFF);

    prep_all<<<768 + 69, 256, 0, stream>>>(inputs, v, W1, W2, b1, b2, bsc, xvT, combo, consts);
    ffm_main<<<SGROUPS * NBB, 512, 0, stream>>>(xvT, combo, partial);
    finalize<<<BATCH / 256, 256, 0, stream>>>(inputs, w, consts, partial, out);
}

// Round 10
// 137.066 us; speedup vs baseline: 1.1073x; 1.1073x over previous
//
#include <hip/hip_runtime.h>
#include <hip/hip_bf16.h>
#include <math.h>

#define BATCH   8192
#define NFIELD  24
#define FAC     16
#define PAIRS   276
#define NSETS   24             // 23 real 12-pair sets + 1 idle set
#define SETLEN  12
#define NBB     (BATCH / 64)   // 128 batch blocks of 64 rows

typedef __attribute__((ext_vector_type(8))) __bf16 bf16x8;
typedef __attribute__((ext_vector_type(4))) float f32x4;

// ---- workspace layout (bytes) ----
// xvT:   [128][24][2][64][8] bf16 = 6,291,456
// combo: [276 + 2 pad][4608]      = 1,281,024
// partial:[24][8192] f32          =   786,432
// wval:  [24][8192] f32           =   786,432
// consts: [1] f32
#define XVT_OFF   0
#define COMBO_OFF 6291456
#define PART_OFF  (COMBO_OFF + 1285632)
#define WVAL_OFF  (PART_OFF + 786432)
#define CONST_OFF (WVAL_OFF + 786432)

// Fused prep: blocks [0,768) gather v->xvT (+ w linear term -> wval);
// blocks [768,837) repack weights.
__global__ void prep_all(const int* __restrict__ inputs,
                         const float* __restrict__ v,
                         const float* __restrict__ w,
                         const float* __restrict__ W1,
                         const float* __restrict__ W2,
                         const float* __restrict__ b1,
                         const float* __restrict__ b2,
                         const float* __restrict__ bsc,
                         __hip_bfloat16* __restrict__ xvT,
                         char* __restrict__ combo,
                         float* __restrict__ wval,
                         float* __restrict__ consts) {
    __shared__ float red[256];
    int blk = blockIdx.x;
    if (blk < 768) {
        int t = blk * 256 + threadIdx.x;          // < 196608
        int field = t >> 13;
        int b = t & 8191;
        int idx = inputs[b * NFIELD + field];
        const float4* src = (const float4*)(v + (long)idx * FAC);
        union { __hip_bfloat16 h[16]; uint4 u[2]; } tmp;
        float4 a0 = src[0], a1 = src[1], a2 = src[2], a3 = src[3];
        tmp.h[0]  = __float2bfloat16(a0.x); tmp.h[1]  = __float2bfloat16(a0.y);
        tmp.h[2]  = __float2bfloat16(a0.z); tmp.h[3]  = __float2bfloat16(a0.w);
        tmp.h[4]  = __float2bfloat16(a1.x); tmp.h[5]  = __float2bfloat16(a1.y);
        tmp.h[6]  = __float2bfloat16(a1.z); tmp.h[7]  = __float2bfloat16(a1.w);
        tmp.h[8]  = __float2bfloat16(a2.x); tmp.h[9]  = __float2bfloat16(a2.y);
        tmp.h[10] = __float2bfloat16(a2.z); tmp.h[11] = __float2bfloat16(a2.w);
        tmp.h[12] = __float2bfloat16(a3.x); tmp.h[13] = __float2bfloat16(a3.y);
        tmp.h[14] = __float2bfloat16(a3.z); tmp.h[15] = __float2bfloat16(a3.w);
        int bb = b >> 6, row = b & 63;
        __hip_bfloat16* base = xvT + (long)bb * 24576 + field * 1024 + row * 8;
        *(uint4*)base         = tmp.u[0];
        *(uint4*)(base + 512) = tmp.u[1];
        // linear-term gather, coalesced write (read by finalize)
        wval[field * BATCH + b] = w[idx];
    } else {
        int wb = blk - 768;                        // 0..68
        int t = wb * 256 + threadIdx.x;            // < 17664
        int p = t >> 6;
        int L = t & 63;
        int q = L >> 4, c = L & 15;
        char* base = combo + (long)p * 4608;
        union { __hip_bfloat16 h[8]; uint4 u; } buf;
#pragma unroll
        for (int tt = 0; tt < 4; ++tt) {
#pragma unroll
            for (int jj = 0; jj < 8; ++jj)
                buf.h[jj] = __float2bfloat16(W1[p * 2048 + (q * 8 + jj) * 64 + tt * 16 + c]);
            *(uint4*)(base + 512 + tt * 1024 + L * 16) = buf.u;
        }
        if (L < 16) {
            float4 bv = {b1[p * 64 + L], b1[p * 64 + 16 + L], b1[p * 64 + 32 + L], b1[p * 64 + 48 + L]};
            *(float4*)(base + L * 16) = bv;
            float4 wv = {W2[p * 64 + L], W2[p * 64 + 16 + L], W2[p * 64 + 32 + L], W2[p * 64 + 48 + L]};
            *(float4*)(base + 256 + L * 16) = wv;
        }
        if (wb == 1) {   // zero the 2 pad pairs (depth-2 tail prefetch reads them)
            uint4 z = {0, 0, 0, 0};
            for (int k = threadIdx.x; k < 576; k += 256)
                *(uint4*)(combo + (long)PAIRS * 4608 + k * 16) = z;
        }
        if (wb == 0) {
            float s = 0.f;
            for (int k = threadIdx.x; k < PAIRS; k += 256) s += b2[k];
            red[threadIdx.x] = s;
            __syncthreads();
            for (int off = 128; off > 0; off >>= 1) {
                if (threadIdx.x < off) red[threadIdx.x] += red[threadIdx.x + off];
                __syncthreads();
            }
            if (threadIdx.x == 0) consts[0] = red[0] + bsc[0];
        }
    }
}

// One pair's weight package in registers. Bias pre-broadcast into persistent
// MFMA C-operands (D!=C, so cb survives and is reused across all 4 row-tiles).
struct Pkg {
    f32x4 cb0, cb1, cb2, cb3;
    float4 mw;
    bf16x8 f0, f1, f2, f3;
};

__device__ __forceinline__ Pkg load_pkg(const char* p, int mcol, int l16) {
    Pkg k;
    float4 tb = *(const float4*)(p + mcol);
    k.cb0 = (f32x4){tb.x, tb.x, tb.x, tb.x};
    k.cb1 = (f32x4){tb.y, tb.y, tb.y, tb.y};
    k.cb2 = (f32x4){tb.z, tb.z, tb.z, tb.z};
    k.cb3 = (f32x4){tb.w, tb.w, tb.w, tb.w};
    k.mw = *(const float4*)(p + 256 + mcol);
    k.f0 = *(const bf16x8*)(p + 512  + l16);
    k.f1 = *(const bf16x8*)(p + 1536 + l16);
    k.f2 = *(const bf16x8*)(p + 2560 + l16);
    k.f3 = *(const bf16x8*)(p + 3584 + l16);
    return k;
}

// Apply one package to all 4 row-tiles. Packed-f32 epilogue (v_pk_max/v_pk_fma).
#define PKGCOMP(P)                                                            \
    {                                                                         \
        int fso = ((quad < 2) ? i : j) * 1088;                                \
        const f32x4 z4 = {0.f, 0.f, 0.f, 0.f};                                \
        _Pragma("unroll")                                                     \
        for (int t = 0; t < 4; ++t) {                                         \
            bf16x8 af = *(const bf16x8*)(xv_s + fso + abase + t * 128);       \
            f32x4 c0 = __builtin_amdgcn_mfma_f32_16x16x32_bf16(af, P.f0, P.cb0, 0, 0, 0); \
            f32x4 c1 = __builtin_amdgcn_mfma_f32_16x16x32_bf16(af, P.f1, P.cb1, 0, 0, 0); \
            f32x4 c2 = __builtin_amdgcn_mfma_f32_16x16x32_bf16(af, P.f2, P.cb2, 0, 0, 0); \
            f32x4 c3 = __builtin_amdgcn_mfma_f32_16x16x32_bf16(af, P.f3, P.cb3, 0, 0, 0); \
            acc[t] = acc[t] + __builtin_elementwise_max(c0, z4) * P.mw.x;     \
            acc[t] = acc[t] + __builtin_elementwise_max(c1, z4) * P.mw.y;     \
            acc[t] = acc[t] + __builtin_elementwise_max(c2, z4) * P.mw.z;     \
            acc[t] = acc[t] + __builtin_elementwise_max(c3, z4) * P.mw.w;     \
        }                                                                     \
        ++j;                                                                  \
        if (j == NFIELD) { ++i; j = i + 1; }                                  \
    }

// 256-thread blocks, one 64-row slab in LDS shared by 4 waves; each wave owns
// a distinct 12-pair set (setid = pg*4+wave), applies each package to 4 row
// tiles. Barrier-free K-loop, depth-2 two-set register prefetch.
__global__ __launch_bounds__(256, 3) void ffm_main(
        const __hip_bfloat16* __restrict__ xvT,
        const char* __restrict__ combo,
        float* __restrict__ partial) {
    // [field][half][row64][8] with +32 elem (64B) pad per 512-elem half-group
    __shared__ __align__(16) __hip_bfloat16 xv_s[24 * 1088];  // 51 KB

    int tid  = threadIdx.x;
    int bb   = blockIdx.x & (NBB - 1);
    int pg   = blockIdx.x >> 7;          // 0..5
    int lane = tid & 63;
    int wave = tid >> 6;
    int col  = lane & 15;
    int quad = lane >> 4;

    // stage 48KB slab: 3072 16B chunks, swizzle ch -> elem ch*8 + (ch>>6)*32
    {
        const uint4* src = (const uint4*)(xvT + (long)bb * 24576);
#pragma unroll
        for (int it = 0; it < 12; ++it) {
            int ch = tid + it * 256;
            *(uint4*)(xv_s + ch * 8 + (ch >> 6) * 32) = src[ch];
        }
    }
    __syncthreads();

    int setid = pg * 4 + wave;           // 0..23; set 23 idle (writes zeros)
    f32x4 acc[4];
#pragma unroll
    for (int t = 0; t < 4; ++t) acc[t] = (f32x4){0.f, 0.f, 0.f, 0.f};

    const int abase = (quad & 1) * 544 + col * 8;   // + t*128 per row-tile
    const int mcol  = col * 16;
    const int l16   = lane * 16;

    if (setid < 23) {
        int p0 = setid * SETLEN;
        int i = 0, rem = p0;
        while (rem >= NFIELD - 1 - i) { rem -= NFIELD - 1 - i; ++i; }
        int j = i + 1 + rem;

        const char* wp = combo + (long)p0 * 4608;
        Pkg A = load_pkg(wp, mcol, l16);
        Pkg B = load_pkg(wp + 4608, mcol, l16);

#pragma unroll 2
        for (int k = 0; k < SETLEN; k += 2) {
            PKGCOMP(A)
            A = load_pkg(wp + 2 * 4608, mcol, l16);   // used 2 iters later
            PKGCOMP(B)
            B = load_pkg(wp + 3 * 4608, mcol, l16);
            wp += 2 * 4608;
        }
    }

    // reduce each acc component over the 16 column-lanes within its quad group
#pragma unroll
    for (int m = 1; m < 16; m <<= 1) {
#pragma unroll
        for (int t = 0; t < 4; ++t) {
#pragma unroll
            for (int r = 0; r < 4; ++r) acc[t][r] += __shfl_xor(acc[t][r], m, 64);
        }
    }
    if (col == 0) {
#pragma unroll
        for (int t = 0; t < 4; ++t) {
            f32x4 o = acc[t];
            *(f32x4*)&partial[setid * BATCH + bb * 64 + t * 16 + quad * 4] = o;
        }
    }
}

// Per-row finalize (no cross-lane ops — the R3-R8 post-timing-safe shape).
// All 48 loads are coalesced across threads (stride-BATCH columns) and
// mutually independent, so they overlap into ~2 memory round trips.
__global__ void finalize(const float* __restrict__ wval,
                         const float* __restrict__ consts,
                         const float* __restrict__ partial,
                         float* __restrict__ out) {
    int b = blockIdx.x * 256 + threadIdx.x;   // < 8192
    float s = consts[0];
#pragma unroll
    for (int f = 0; f < NFIELD; ++f) s += wval[f * BATCH + b];
#pragma unroll
    for (int g = 0; g < NSETS; ++g) s += partial[g * BATCH + b];
    out[b] = 1.0f / (1.0f + expf(-s));
}

extern "C" void kernel_launch(void* const* d_in, const int* in_sizes, int n_in,
                              void* d_out, int out_size, void* d_ws, size_t ws_size,
                              hipStream_t stream) {
    const int*   inputs = (const int*)d_in[0];
    const float* w      = (const float*)d_in[1];
    const float* v      = (const float*)d_in[2];
    const float* bsc    = (const float*)d_in[3];
    const float* W1     = (const float*)d_in[4];
    const float* b1     = (const float*)d_in[5];
    const float* W2     = (const float*)d_in[6];
    const float* b2     = (const float*)d_in[7];
    float* out = (float*)d_out;

    char* ws = (char*)d_ws;
    __hip_bfloat16* xvT = (__hip_bfloat16*)(ws + XVT_OFF);
    char*  combo   = ws + COMBO_OFF;
    float* partial = (float*)(ws + PART_OFF);
    float* wval    = (float*)(ws + WVAL_OFF);
    float* consts  = (float*)(ws + CONST_OFF);

    prep_all<<<768 + 69, 256, 0, stream>>>(inputs, v, w, W1, W2, b1, b2, bsc,
                                           xvT, combo, wval, consts);
    ffm_main<<<NBB * 6, 256, 0, stream>>>(xvT, combo, partial);
    finalize<<<BATCH / 256, 256, 0, stream>>>(wval, consts, partial, out);
}